// Round 3
// baseline (476.673 us; speedup 1.0000x reference)
//
#include <hip/hip_runtime.h>

// Deep-Sets actor, round 3: occupancy-first.
// prep: ws16 = [W1T 256x64 | W2T 256x256 | RHOT 256x256 | HEADT 16x256] bf16 (plain)
// main: B/64=1024 blocks x 512 thr (8 waves), M=64 tile, wave owns 32 N-cols.
//   LDS 51200 B static (hbuf 32K swz | inp 8K swz | raw 10.2K) -> 2 blocks/CU
//   __launch_bounds__(512,4): VGPR<=128 -> 16 waves/CU = 4 waves/SIMD.
//   Weights streamed from L2 (proven resident in round 2).

typedef __bf16 bf16x8 __attribute__((ext_vector_type(8)));
typedef float f32x4 __attribute__((ext_vector_type(4)));

#define HB_OFF  0        // hbuf: 64 rows x 512 B, XOR-swizzled        (32768)
#define INP_OFF 32768    // inp:  64 rows x 128 B, XOR-swizzled        ( 8192)
#define RAW_OFF 40960    // raw:  64 rows x 80 bf16                    (10240)
#define LDS_TOTAL 51200

__device__ __forceinline__ unsigned short f2bf(float f) {
  union { float f; unsigned u; } v; v.f = f;
  unsigned r = v.u + 0x7fffu + ((v.u >> 16) & 1u);  // RNE
  return (unsigned short)(r >> 16);
}
__device__ __forceinline__ int swz512(int o) { return o ^ (((o >> 9) & 7) << 4); }
__device__ __forceinline__ int swz128(int o) { return o ^ (((o >> 7) & 7) << 4); }
__device__ __forceinline__ f32x4 mfma16(bf16x8 a, bf16x8 b, f32x4 c) {
  return __builtin_amdgcn_mfma_f32_16x16x32_bf16(a, b, c, 0, 0, 0);
}

__global__ void actor_prep(const float* __restrict__ w1, const float* __restrict__ w2,
                           const float* __restrict__ rho, const float* __restrict__ mw,
                           const float* __restrict__ lw, unsigned short* __restrict__ ws16) {
  int idx = blockIdx.x * blockDim.x + threadIdx.x;
  const int T = 16384 + 65536 + 65536 + 4096;
  for (; idx < T; idx += gridDim.x * blockDim.x) {
    float v;
    if (idx < 16384) {                 // W1T[n][k], k padded 58->64
      int n = idx >> 6, k = idx & 63;
      v = (k < 58) ? w1[k * 256 + n] : 0.f;
    } else if (idx < 81920) {          // W2T[n][k]
      int o = idx - 16384; int n = o >> 8, k = o & 255;
      v = w2[k * 256 + n];
    } else if (idx < 147456) {         // RHOT[n][k]
      int o = idx - 81920; int n = o >> 8, k = o & 255;
      v = rho[k * 256 + n];
    } else {                           // HEADT[n][k]
      int o = idx - 147456; int n = o >> 8, k = o & 255;
      v = (n < 4) ? mw[k * 4 + n] : ((n < 8) ? lw[k * 4 + (n - 4)] : 0.f);
    }
    ws16[idx] = f2bf(v);
  }
}

__global__ __launch_bounds__(512, 4) void actor_main(
    const float* __restrict__ obs, const float* __restrict__ ag, const float* __restrict__ g,
    const float* __restrict__ b1v, const float* __restrict__ b2v, const float* __restrict__ rbv,
    const float* __restrict__ mbv, const float* __restrict__ lbv,
    const unsigned short* __restrict__ ws16,
    float* __restrict__ out, int B) {
  __shared__ char smem[LDS_TOTAL];
  unsigned short* rawp = (unsigned short*)(smem + RAW_OFF);

  const unsigned short* w1t   = ws16;
  const unsigned short* w2t   = ws16 + 16384;
  const unsigned short* rhot  = ws16 + 81920;
  const unsigned short* headt = ws16 + 147456;

  const int tid = threadIdx.x;
  const int lane = tid & 63;
  const int wv = tid >> 6;       // 0..7
  const int l15 = lane & 15;
  const int lq = lane >> 4;
  const int wbase = wv * 32;     // 32-col N-strip
  const long brow = (long)blockIdx.x * 64;
  const f32x4 fzero = {0.f, 0.f, 0.f, 0.f};

  // ---- stage raw inputs as bf16 ----
  for (int i = tid; i < 64 * 55; i += 512) {
    int r = i / 55, c = i - r * 55;
    rawp[r * 80 + c] = f2bf(obs[brow * 55 + i]);
  }
  for (int i = tid; i < 64 * 9; i += 512) {
    int r = i / 9, c = i - r * 9;
    rawp[r * 80 + 56 + c] = f2bf(ag[brow * 9 + i]);
    rawp[r * 80 + 65 + c] = f2bf(g[brow * 9 + i]);
  }
  if (tid < 64) {
    rawp[tid * 80 + 74] = 0;
    rawp[tid * 80 + 75] = 0x3F80;  // bf16(1.0)
  }

  float b1r[2], b2r[2], rbr[2];
#pragma unroll
  for (int nt = 0; nt < 2; nt++) {
    b1r[nt] = b1v[wbase + nt * 16 + l15];
    b2r[nt] = b2v[wbase + nt * 16 + l15];
    rbr[nt] = rbv[wbase + nt * 16 + l15];
  }

  f32x4 pooled[4][2];
#pragma unroll
  for (int a = 0; a < 4; a++)
#pragma unroll
    for (int b = 0; b < 2; b++) pooled[a][b] = fzero;

  const int PI[6] = {0, 0, 1, 1, 2, 2};
  const int PJ[6] = {1, 2, 0, 2, 0, 1};

  __syncthreads();  // raw ready

  for (int p = 0; p < 6; p++) {
    const int pi = PI[p], pj = PJ[p];
    // ---- build inp tile (swizzled [64][64] bf16); col fixed per thread ----
    {
      int c = tid & 63, s;
      if (c < 3)       s = 56 + 3 * pi + c;
      else if (c < 6)  s = 56 + 3 * pj + (c - 3);
      else if (c < 9)  s = 65 + 3 * pi + (c - 6);
      else if (c < 12) s = 65 + 3 * pj + (c - 9);
      else if (c < 22) s = c - 12;
      else if (c < 25) s = ((c - 22) == pi) ? 75 : 74;
      else if (c < 40) s = 10 + 15 * pi + (c - 25);
      else if (c < 43) s = ((c - 40) == pj) ? 75 : 74;
      else if (c < 58) s = 10 + 15 * pj + (c - 43);
      else             s = 74;
      int r0 = tid >> 6;
#pragma unroll
      for (int k = 0; k < 8; k++) {
        int r = r0 + 8 * k;
        *(unsigned short*)(smem + INP_OFF + swz128(r * 128 + c * 2)) = rawp[r * 80 + s];
      }
    }
    __syncthreads();  // inp ready; prev perm's hbuf reads all done

    // ---- GEMM1: h = relu(inp @ W1 + b1) ----
    f32x4 acc1[4][2];
#pragma unroll
    for (int a = 0; a < 4; a++)
#pragma unroll
      for (int b = 0; b < 2; b++) acc1[a][b] = fzero;
#pragma unroll
    for (int kk = 0; kk < 2; kk++) {
      bf16x8 a1[4], w1f[2];
#pragma unroll
      for (int nt = 0; nt < 2; nt++)
        w1f[nt] = *(const bf16x8*)&w1t[(wbase + nt * 16 + l15) * 64 + kk * 32 + lq * 8];
#pragma unroll
      for (int mt = 0; mt < 4; mt++)
        a1[mt] = *(const bf16x8*)(smem + INP_OFF +
                   swz128((mt * 16 + l15) * 128 + (kk * 32 + lq * 8) * 2));
#pragma unroll
      for (int mt = 0; mt < 4; mt++)
#pragma unroll
        for (int nt = 0; nt < 2; nt++)
          acc1[mt][nt] = mfma16(a1[mt], w1f[nt], acc1[mt][nt]);
    }
#pragma unroll
    for (int nt = 0; nt < 2; nt++)
#pragma unroll
      for (int mt = 0; mt < 4; mt++)
#pragma unroll
        for (int r = 0; r < 4; r++) {
          float hv = fmaxf(acc1[mt][nt][r] + b1r[nt], 0.f);
          int row = mt * 16 + lq * 4 + r, col = wbase + nt * 16 + l15;
          *(unsigned short*)(smem + HB_OFF + swz512(row * 512 + col * 2)) = f2bf(hv);
        }
    __syncthreads();  // hbuf ready

    // ---- GEMM2: pooled += relu(h @ W2 + b2); B from L2 ----
    f32x4 acc2[4][2];
#pragma unroll
    for (int a = 0; a < 4; a++)
#pragma unroll
      for (int b = 0; b < 2; b++) acc2[a][b] = fzero;
#pragma unroll
    for (int kk = 0; kk < 8; kk++) {
      bf16x8 a2[4], b2f[2];
#pragma unroll
      for (int nt = 0; nt < 2; nt++)
        b2f[nt] = *(const bf16x8*)&w2t[(wbase + nt * 16 + l15) * 256 + kk * 32 + lq * 8];
#pragma unroll
      for (int mt = 0; mt < 4; mt++)
        a2[mt] = *(const bf16x8*)(smem + HB_OFF +
                   swz512((mt * 16 + l15) * 512 + (kk * 32 + lq * 8) * 2));
#pragma unroll
      for (int mt = 0; mt < 4; mt++)
#pragma unroll
        for (int nt = 0; nt < 2; nt++)
          acc2[mt][nt] = mfma16(a2[mt], b2f[nt], acc2[mt][nt]);
    }
#pragma unroll
    for (int nt = 0; nt < 2; nt++)
#pragma unroll
      for (int mt = 0; mt < 4; mt++)
#pragma unroll
        for (int r = 0; r < 4; r++)
          pooled[mt][nt][r] += fmaxf(acc2[mt][nt][r] + b2r[nt], 0.f);
    // no barrier: next perm's post-build barrier orders hbuf overwrite after reads
  }

  __syncthreads();  // all GEMM2 reads done
  // ---- pooled -> hbuf ----
#pragma unroll
  for (int nt = 0; nt < 2; nt++)
#pragma unroll
    for (int mt = 0; mt < 4; mt++)
#pragma unroll
      for (int r = 0; r < 4; r++) {
        int row = mt * 16 + lq * 4 + r, col = wbase + nt * 16 + l15;
        *(unsigned short*)(smem + HB_OFF + swz512(row * 512 + col * 2)) =
            f2bf(pooled[mt][nt][r]);
      }
  __syncthreads();

  // ---- GEMM3: x = relu(pooled @ rho + rb) ----
  f32x4 acc3[4][2];
#pragma unroll
  for (int a = 0; a < 4; a++)
#pragma unroll
    for (int b = 0; b < 2; b++) acc3[a][b] = fzero;
#pragma unroll
  for (int kk = 0; kk < 8; kk++) {
    bf16x8 a3[4], b3f[2];
#pragma unroll
    for (int nt = 0; nt < 2; nt++)
      b3f[nt] = *(const bf16x8*)&rhot[(wbase + nt * 16 + l15) * 256 + kk * 32 + lq * 8];
#pragma unroll
    for (int mt = 0; mt < 4; mt++)
      a3[mt] = *(const bf16x8*)(smem + HB_OFF +
                 swz512((mt * 16 + l15) * 512 + (kk * 32 + lq * 8) * 2));
#pragma unroll
    for (int mt = 0; mt < 4; mt++)
#pragma unroll
      for (int nt = 0; nt < 2; nt++)
        acc3[mt][nt] = mfma16(a3[mt], b3f[nt], acc3[mt][nt]);
  }
  __syncthreads();  // hbuf reads done before overwrite
#pragma unroll
  for (int nt = 0; nt < 2; nt++)
#pragma unroll
    for (int mt = 0; mt < 4; mt++)
#pragma unroll
      for (int r = 0; r < 4; r++) {
        float xv = fmaxf(acc3[mt][nt][r] + rbr[nt], 0.f);
        int row = mt * 16 + lq * 4 + r, col = wbase + nt * 16 + l15;
        *(unsigned short*)(smem + HB_OFF + swz512(row * 512 + col * 2)) = f2bf(xv);
      }
  __syncthreads();

  // ---- GEMM4: heads; waves 0-3 own 16 rows each ----
  if (wv < 4) {
    f32x4 acc4 = fzero;
#pragma unroll
    for (int kk = 0; kk < 8; kk++) {
      bf16x8 a = *(const bf16x8*)(smem + HB_OFF +
                   swz512((wv * 16 + l15) * 512 + (kk * 32 + lq * 8) * 2));
      bf16x8 b = *(const bf16x8*)&headt[l15 * 256 + kk * 32 + lq * 8];
      acc4 = mfma16(a, b, acc4);
    }
#pragma unroll
    for (int r = 0; r < 4; r++) {
      long gr = brow + wv * 16 + lq * 4 + r;
      if (l15 < 4) {
        out[gr * 4 + l15] = acc4[r] + mbv[l15];
      } else if (l15 < 8) {
        float u = fminf(fmaxf(acc4[r] + lbv[l15 - 4], -20.f), 2.f);
        out[(long)B * 4 + gr * 4 + (l15 - 4)] = u;
      }
    }
  }
}

extern "C" void kernel_launch(void* const* d_in, const int* in_sizes, int n_in,
                              void* d_out, int out_size, void* d_ws, size_t ws_size,
                              hipStream_t stream) {
  const float* obs = (const float*)d_in[0];
  const float* ag  = (const float*)d_in[1];
  const float* g   = (const float*)d_in[2];
  const float* w1  = (const float*)d_in[3];
  const float* b1  = (const float*)d_in[4];
  const float* w2  = (const float*)d_in[5];
  const float* b2  = (const float*)d_in[6];
  const float* rw  = (const float*)d_in[7];
  const float* rb  = (const float*)d_in[8];
  const float* mw  = (const float*)d_in[9];
  const float* mb  = (const float*)d_in[10];
  const float* lw  = (const float*)d_in[11];
  const float* lb  = (const float*)d_in[12];
  int B = in_sizes[0] / 55;

  unsigned short* ws16 = (unsigned short*)d_ws;
  hipLaunchKernelGGL(actor_prep, dim3(128), dim3(256), 0, stream, w1, w2, rw, mw, lw, ws16);
  hipLaunchKernelGGL(actor_main, dim3(B / 64), dim3(512), 0, stream,
                     obs, ag, g, b1, b2, rb, mb, lb, ws16, (float*)d_out, B);
}

// Round 4
// 151.437 us; speedup vs baseline: 3.1477x; 3.1477x over previous
//
#include <hip/hip_runtime.h>

// Deep-Sets actor, round 4: round-3 structure, spill fixed.
// __launch_bounds__(512,2): VGPR cap 128 (observed: arg4 -> cap 64 -> spills).
// main: B/64=1024 blocks x 512 thr (8 waves), M=64 tile, wave owns 32 N-cols.
//   LDS 51200 B static -> 2 blocks/CU, 16 waves/CU = 4 waves/SIMD.
//   Weights streamed from L2.

typedef __bf16 bf16x8 __attribute__((ext_vector_type(8)));
typedef float f32x4 __attribute__((ext_vector_type(4)));

#define HB_OFF  0        // hbuf: 64 rows x 512 B, XOR-swizzled        (32768)
#define INP_OFF 32768    // inp:  64 rows x 128 B, XOR-swizzled        ( 8192)
#define RAW_OFF 40960    // raw:  64 rows x 80 bf16                    (10240)
#define LDS_TOTAL 51200

__device__ __forceinline__ unsigned short f2bf(float f) {
  union { float f; unsigned u; } v; v.f = f;
  unsigned r = v.u + 0x7fffu + ((v.u >> 16) & 1u);  // RNE
  return (unsigned short)(r >> 16);
}
__device__ __forceinline__ int swz512(int o) { return o ^ (((o >> 9) & 7) << 4); }
__device__ __forceinline__ int swz128(int o) { return o ^ (((o >> 7) & 7) << 4); }
__device__ __forceinline__ f32x4 mfma16(bf16x8 a, bf16x8 b, f32x4 c) {
  return __builtin_amdgcn_mfma_f32_16x16x32_bf16(a, b, c, 0, 0, 0);
}

__global__ void actor_prep(const float* __restrict__ w1, const float* __restrict__ w2,
                           const float* __restrict__ rho, const float* __restrict__ mw,
                           const float* __restrict__ lw, unsigned short* __restrict__ ws16) {
  int idx = blockIdx.x * blockDim.x + threadIdx.x;
  const int T = 16384 + 65536 + 65536 + 4096;
  for (; idx < T; idx += gridDim.x * blockDim.x) {
    float v;
    if (idx < 16384) {                 // W1T[n][k], k padded 58->64
      int n = idx >> 6, k = idx & 63;
      v = (k < 58) ? w1[k * 256 + n] : 0.f;
    } else if (idx < 81920) {          // W2T[n][k]
      int o = idx - 16384; int n = o >> 8, k = o & 255;
      v = w2[k * 256 + n];
    } else if (idx < 147456) {         // RHOT[n][k]
      int o = idx - 81920; int n = o >> 8, k = o & 255;
      v = rho[k * 256 + n];
    } else {                           // HEADT[n][k]
      int o = idx - 147456; int n = o >> 8, k = o & 255;
      v = (n < 4) ? mw[k * 4 + n] : ((n < 8) ? lw[k * 4 + (n - 4)] : 0.f);
    }
    ws16[idx] = f2bf(v);
  }
}

__global__ __launch_bounds__(512, 2) void actor_main(
    const float* __restrict__ obs, const float* __restrict__ ag, const float* __restrict__ g,
    const float* __restrict__ b1v, const float* __restrict__ b2v, const float* __restrict__ rbv,
    const float* __restrict__ mbv, const float* __restrict__ lbv,
    const unsigned short* __restrict__ ws16,
    float* __restrict__ out, int B) {
  __shared__ char smem[LDS_TOTAL];
  unsigned short* rawp = (unsigned short*)(smem + RAW_OFF);

  const unsigned short* w1t   = ws16;
  const unsigned short* w2t   = ws16 + 16384;
  const unsigned short* rhot  = ws16 + 81920;
  const unsigned short* headt = ws16 + 147456;

  const int tid = threadIdx.x;
  const int lane = tid & 63;
  const int wv = tid >> 6;       // 0..7
  const int l15 = lane & 15;
  const int lq = lane >> 4;
  const int wbase = wv * 32;     // 32-col N-strip
  const long brow = (long)blockIdx.x * 64;
  const f32x4 fzero = {0.f, 0.f, 0.f, 0.f};

  // ---- stage raw inputs as bf16 ----
  for (int i = tid; i < 64 * 55; i += 512) {
    int r = i / 55, c = i - r * 55;
    rawp[r * 80 + c] = f2bf(obs[brow * 55 + i]);
  }
  for (int i = tid; i < 64 * 9; i += 512) {
    int r = i / 9, c = i - r * 9;
    rawp[r * 80 + 56 + c] = f2bf(ag[brow * 9 + i]);
    rawp[r * 80 + 65 + c] = f2bf(g[brow * 9 + i]);
  }
  if (tid < 64) {
    rawp[tid * 80 + 74] = 0;
    rawp[tid * 80 + 75] = 0x3F80;  // bf16(1.0)
  }

  float b1r[2], b2r[2], rbr[2];
#pragma unroll
  for (int nt = 0; nt < 2; nt++) {
    b1r[nt] = b1v[wbase + nt * 16 + l15];
    b2r[nt] = b2v[wbase + nt * 16 + l15];
    rbr[nt] = rbv[wbase + nt * 16 + l15];
  }

  f32x4 pooled[4][2];
#pragma unroll
  for (int a = 0; a < 4; a++)
#pragma unroll
    for (int b = 0; b < 2; b++) pooled[a][b] = fzero;

  const int PI[6] = {0, 0, 1, 1, 2, 2};
  const int PJ[6] = {1, 2, 0, 2, 0, 1};

  __syncthreads();  // raw ready

  for (int p = 0; p < 6; p++) {
    const int pi = PI[p], pj = PJ[p];
    // ---- build inp tile (swizzled [64][64] bf16); col fixed per thread ----
    {
      int c = tid & 63, s;
      if (c < 3)       s = 56 + 3 * pi + c;
      else if (c < 6)  s = 56 + 3 * pj + (c - 3);
      else if (c < 9)  s = 65 + 3 * pi + (c - 6);
      else if (c < 12) s = 65 + 3 * pj + (c - 9);
      else if (c < 22) s = c - 12;
      else if (c < 25) s = ((c - 22) == pi) ? 75 : 74;
      else if (c < 40) s = 10 + 15 * pi + (c - 25);
      else if (c < 43) s = ((c - 40) == pj) ? 75 : 74;
      else if (c < 58) s = 10 + 15 * pj + (c - 43);
      else             s = 74;
      int r0 = tid >> 6;
#pragma unroll
      for (int k = 0; k < 8; k++) {
        int r = r0 + 8 * k;
        *(unsigned short*)(smem + INP_OFF + swz128(r * 128 + c * 2)) = rawp[r * 80 + s];
      }
    }
    __syncthreads();  // inp ready; prev perm's hbuf reads all done

    // ---- GEMM1: h = relu(inp @ W1 + b1) ----
    f32x4 acc1[4][2];
#pragma unroll
    for (int a = 0; a < 4; a++)
#pragma unroll
      for (int b = 0; b < 2; b++) acc1[a][b] = fzero;
#pragma unroll
    for (int kk = 0; kk < 2; kk++) {
      bf16x8 a1[4], w1f[2];
#pragma unroll
      for (int nt = 0; nt < 2; nt++)
        w1f[nt] = *(const bf16x8*)&w1t[(wbase + nt * 16 + l15) * 64 + kk * 32 + lq * 8];
#pragma unroll
      for (int mt = 0; mt < 4; mt++)
        a1[mt] = *(const bf16x8*)(smem + INP_OFF +
                   swz128((mt * 16 + l15) * 128 + (kk * 32 + lq * 8) * 2));
#pragma unroll
      for (int mt = 0; mt < 4; mt++)
#pragma unroll
        for (int nt = 0; nt < 2; nt++)
          acc1[mt][nt] = mfma16(a1[mt], w1f[nt], acc1[mt][nt]);
    }
#pragma unroll
    for (int nt = 0; nt < 2; nt++)
#pragma unroll
      for (int mt = 0; mt < 4; mt++)
#pragma unroll
        for (int r = 0; r < 4; r++) {
          float hv = fmaxf(acc1[mt][nt][r] + b1r[nt], 0.f);
          int row = mt * 16 + lq * 4 + r, col = wbase + nt * 16 + l15;
          *(unsigned short*)(smem + HB_OFF + swz512(row * 512 + col * 2)) = f2bf(hv);
        }
    __syncthreads();  // hbuf ready

    // ---- GEMM2: pooled += relu(h @ W2 + b2); B from L2 ----
    f32x4 acc2[4][2];
#pragma unroll
    for (int a = 0; a < 4; a++)
#pragma unroll
      for (int b = 0; b < 2; b++) acc2[a][b] = fzero;
#pragma unroll
    for (int kk = 0; kk < 8; kk++) {
      bf16x8 a2[4], b2f[2];
#pragma unroll
      for (int nt = 0; nt < 2; nt++)
        b2f[nt] = *(const bf16x8*)&w2t[(wbase + nt * 16 + l15) * 256 + kk * 32 + lq * 8];
#pragma unroll
      for (int mt = 0; mt < 4; mt++)
        a2[mt] = *(const bf16x8*)(smem + HB_OFF +
                   swz512((mt * 16 + l15) * 512 + (kk * 32 + lq * 8) * 2));
#pragma unroll
      for (int mt = 0; mt < 4; mt++)
#pragma unroll
        for (int nt = 0; nt < 2; nt++)
          acc2[mt][nt] = mfma16(a2[mt], b2f[nt], acc2[mt][nt]);
    }
#pragma unroll
    for (int nt = 0; nt < 2; nt++)
#pragma unroll
      for (int mt = 0; mt < 4; mt++)
#pragma unroll
        for (int r = 0; r < 4; r++)
          pooled[mt][nt][r] += fmaxf(acc2[mt][nt][r] + b2r[nt], 0.f);
    // no barrier: next perm's post-build barrier orders hbuf overwrite after reads
  }

  __syncthreads();  // all GEMM2 reads done
  // ---- pooled -> hbuf ----
#pragma unroll
  for (int nt = 0; nt < 2; nt++)
#pragma unroll
    for (int mt = 0; mt < 4; mt++)
#pragma unroll
      for (int r = 0; r < 4; r++) {
        int row = mt * 16 + lq * 4 + r, col = wbase + nt * 16 + l15;
        *(unsigned short*)(smem + HB_OFF + swz512(row * 512 + col * 2)) =
            f2bf(pooled[mt][nt][r]);
      }
  __syncthreads();

  // ---- GEMM3: x = relu(pooled @ rho + rb) ----
  f32x4 acc3[4][2];
#pragma unroll
  for (int a = 0; a < 4; a++)
#pragma unroll
    for (int b = 0; b < 2; b++) acc3[a][b] = fzero;
#pragma unroll
  for (int kk = 0; kk < 8; kk++) {
    bf16x8 a3[4], b3f[2];
#pragma unroll
    for (int nt = 0; nt < 2; nt++)
      b3f[nt] = *(const bf16x8*)&rhot[(wbase + nt * 16 + l15) * 256 + kk * 32 + lq * 8];
#pragma unroll
    for (int mt = 0; mt < 4; mt++)
      a3[mt] = *(const bf16x8*)(smem + HB_OFF +
                 swz512((mt * 16 + l15) * 512 + (kk * 32 + lq * 8) * 2));
#pragma unroll
    for (int mt = 0; mt < 4; mt++)
#pragma unroll
      for (int nt = 0; nt < 2; nt++)
        acc3[mt][nt] = mfma16(a3[mt], b3f[nt], acc3[mt][nt]);
  }
  __syncthreads();  // hbuf reads done before overwrite
#pragma unroll
  for (int nt = 0; nt < 2; nt++)
#pragma unroll
    for (int mt = 0; mt < 4; mt++)
#pragma unroll
      for (int r = 0; r < 4; r++) {
        float xv = fmaxf(acc3[mt][nt][r] + rbr[nt], 0.f);
        int row = mt * 16 + lq * 4 + r, col = wbase + nt * 16 + l15;
        *(unsigned short*)(smem + HB_OFF + swz512(row * 512 + col * 2)) = f2bf(xv);
      }
  __syncthreads();

  // ---- GEMM4: heads; waves 0-3 own 16 rows each ----
  if (wv < 4) {
    f32x4 acc4 = fzero;
#pragma unroll
    for (int kk = 0; kk < 8; kk++) {
      bf16x8 a = *(const bf16x8*)(smem + HB_OFF +
                   swz512((wv * 16 + l15) * 512 + (kk * 32 + lq * 8) * 2));
      bf16x8 b = *(const bf16x8*)&headt[l15 * 256 + kk * 32 + lq * 8];
      acc4 = mfma16(a, b, acc4);
    }
#pragma unroll
    for (int r = 0; r < 4; r++) {
      long gr = brow + wv * 16 + lq * 4 + r;
      if (l15 < 4) {
        out[gr * 4 + l15] = acc4[r] + mbv[l15];
      } else if (l15 < 8) {
        float u = fminf(fmaxf(acc4[r] + lbv[l15 - 4], -20.f), 2.f);
        out[(long)B * 4 + gr * 4 + (l15 - 4)] = u;
      }
    }
  }
}

extern "C" void kernel_launch(void* const* d_in, const int* in_sizes, int n_in,
                              void* d_out, int out_size, void* d_ws, size_t ws_size,
                              hipStream_t stream) {
  const float* obs = (const float*)d_in[0];
  const float* ag  = (const float*)d_in[1];
  const float* g   = (const float*)d_in[2];
  const float* w1  = (const float*)d_in[3];
  const float* b1  = (const float*)d_in[4];
  const float* w2  = (const float*)d_in[5];
  const float* b2  = (const float*)d_in[6];
  const float* rw  = (const float*)d_in[7];
  const float* rb  = (const float*)d_in[8];
  const float* mw  = (const float*)d_in[9];
  const float* mb  = (const float*)d_in[10];
  const float* lw  = (const float*)d_in[11];
  const float* lb  = (const float*)d_in[12];
  int B = in_sizes[0] / 55;

  unsigned short* ws16 = (unsigned short*)d_ws;
  hipLaunchKernelGGL(actor_prep, dim3(128), dim3(256), 0, stream, w1, w2, rw, mw, lw, ws16);
  hipLaunchKernelGGL(actor_main, dim3(B / 64), dim3(512), 0, stream,
                     obs, ag, g, b1, b2, rb, mb, lb, ws16, (float*)d_out, B);
}